// Round 1
// baseline (445.358 us; speedup 1.0000x reference)
//
#include <hip/hip_runtime.h>
#include <cstdint>
#include <cstddef>

typedef __attribute__((ext_vector_type(4))) float f32x4;
typedef __attribute__((ext_vector_type(8))) short bf16x8;

#define S_LEN   2048
#define HID     4096
#define NH      32
#define NKV     8
#define HD      128
#define QKV_N   6144   /* 4096 Q + 1024 K + 1024 V */

typedef const __attribute__((address_space(1))) unsigned int* gptr_t;
typedef __attribute__((address_space(3))) unsigned int* lptr_t;

__device__ __forceinline__ void gload_lds16(const void* g, void* l) {
  __builtin_amdgcn_global_load_lds((gptr_t)g, (lptr_t)l, 16, 0, 0);
}

__device__ __forceinline__ ushort f2bf(float f) {
  union { float f; uint32_t u; } v; v.f = f;
  uint32_t r = v.u + 0x7FFFu + ((v.u >> 16) & 1u);
  return (ushort)(r >> 16);
}
__device__ __forceinline__ float bf2f(ushort u) {
  union { uint32_t u; float f; } v; v.u = ((uint32_t)u) << 16;
  return v.f;
}

// ---------------- cast f32 -> bf16 (vectorized) ----------------
__global__ void cast_f32_bf16(const float* __restrict__ in, ushort* __restrict__ out, int n) {
  int i = (blockIdx.x * 256 + threadIdx.x) * 4;
  if (i >= n) return;
  float4 v = *reinterpret_cast<const float4*>(in + i);
  ushort4 o;
  o.x = f2bf(v.x); o.y = f2bf(v.y); o.z = f2bf(v.z); o.w = f2bf(v.w);
  *reinterpret_cast<ushort4*>(out + i) = o;
}

// ---------------- transpose + cast: in f32 [R][C] -> out bf16 [C][R] ----------------
__global__ void transpose_cast(const float* __restrict__ in, ushort* __restrict__ out, int R, int C) {
  __shared__ float t[32][33];
  int tx = threadIdx.x & 31, ty = threadIdx.x >> 5;  // 32 x 8
  int r0 = blockIdx.y * 32, c0 = blockIdx.x * 32;
#pragma unroll
  for (int i = 0; i < 32; i += 8)
    t[ty + i][tx] = in[(size_t)(r0 + ty + i) * C + c0 + tx];
  __syncthreads();
#pragma unroll
  for (int i = 0; i < 32; i += 8)
    out[(size_t)(c0 + ty + i) * R + r0 + tx] = f2bf(t[tx][ty + i]);
}

// ---------------- GEMM: C[M][N] = A[M][K] * B^T  (B stored [N][K]), bf16 in, fp32 acc ----------------
// m97 structure: 128x128 tile, BK=32, 4 waves (2x2), each wave 64x64 (4x4 frags of 16x16x32)
template <bool BF16_OUT>
__global__ __launch_bounds__(256, 2) void gemm_bt(
    const ushort* __restrict__ A, const ushort* __restrict__ B,
    void* __restrict__ Cp, int M, int N, int K) {
  __shared__ ushort a_lds[128 * 32];
  __shared__ ushort b_lds[128 * 32];
  const int tid = threadIdx.x;
  const int wid = tid >> 6, lane = tid & 63;
  const int l16 = lane & 15, lk = lane >> 4;
  const int wr = wid >> 1, wc = wid & 1;
  const size_t a_row0 = (size_t)blockIdx.y * 128;
  const size_t b_row0 = (size_t)blockIdx.x * 128;

  f32x4 acc[4][4] = {};

  for (int kt = 0; kt < K; kt += 32) {
    __syncthreads();  // prior-iteration LDS reads complete before overwrite
#pragma unroll
    for (int i = 0; i < 2; ++i) {
      int c = i * 256 + wid * 64 + lane;   // 16B chunk index, 512 chunks per tile
      int row = c >> 2, cc = c & 3;        // 4 chunks per 64B row
      gload_lds16(A + (a_row0 + row) * K + kt + cc * 8, &a_lds[c * 8]);
      gload_lds16(B + (b_row0 + row) * K + kt + cc * 8, &b_lds[c * 8]);
    }
    __syncthreads();  // drains vmcnt: LDS tiles ready

    bf16x8 af[4], bf[4];
#pragma unroll
    for (int m = 0; m < 4; ++m)
      af[m] = *reinterpret_cast<const bf16x8*>(&a_lds[(wr * 64 + m * 16 + l16) * 32 + lk * 8]);
#pragma unroll
    for (int n = 0; n < 4; ++n)
      bf[n] = *reinterpret_cast<const bf16x8*>(&b_lds[(wc * 64 + n * 16 + l16) * 32 + lk * 8]);
#pragma unroll
    for (int m = 0; m < 4; ++m)
#pragma unroll
      for (int n = 0; n < 4; ++n)
        acc[m][n] = __builtin_amdgcn_mfma_f32_16x16x32_bf16(af[m], bf[n], acc[m][n], 0, 0, 0);
  }

#pragma unroll
  for (int m = 0; m < 4; ++m) {
    int row_b = wr * 64 + m * 16 + lk * 4;
#pragma unroll
    for (int n = 0; n < 4; ++n) {
      int col = (int)b_row0 + wc * 64 + n * 16 + l16;
#pragma unroll
      for (int r = 0; r < 4; ++r) {
        size_t row = a_row0 + row_b + r;
        if constexpr (BF16_OUT)
          ((ushort*)Cp)[row * N + col] = f2bf(acc[m][n][r]);
        else
          ((float*)Cp)[row * N + col] = acc[m][n][r];
      }
    }
  }
}

// ---------------- RoPE in-place on Q (cols 0..4095) and K (cols 4096..5119) of QKV ----------------
__global__ void rope_kernel(ushort* __restrict__ QKV) {
  int idx = blockIdx.x * 256 + threadIdx.x;  // 2048 * 40 * 8 threads
  int dg = idx & 7;
  int t = idx >> 3;
  int s = t / 40;
  int hh = t - s * 40;
  if (s >= S_LEN) return;
  int col = (hh < NH) ? hh * HD : HID + (hh - NH) * HD;
  ushort* base = QKV + (size_t)s * QKV_N + col + dg * 8;

  union U { uint4 v; ushort u[8]; };
  U L, H, OL, OH;
  L.v = *reinterpret_cast<const uint4*>(base);
  H.v = *reinterpret_cast<const uint4*>(base + 64);
  const float C0 = 13.287712379549449f / 64.0f;  // log2(10000)/64
#pragma unroll
  for (int j = 0; j < 8; ++j) {
    int d = dg * 8 + j;
    float invf = exp2f(-(float)d * C0);
    float ang = (float)s * invf;
    float sn, cs;
    sincosf(ang, &sn, &cs);
    float xl = bf2f(L.u[j]), xh = bf2f(H.u[j]);
    OL.u[j] = f2bf(xl * cs - xh * sn);
    OH.u[j] = f2bf(xh * cs + xl * sn);
  }
  *reinterpret_cast<uint4*>(base) = OL.v;
  *reinterpret_cast<uint4*>(base + 64) = OH.v;
}

// ---------------- V slice of QKV -> Vt[8][128][2048] ----------------
__global__ void transpose_v(const ushort* __restrict__ QKV, ushort* __restrict__ Vt) {
  __shared__ ushort t[64][65];
  int s0 = blockIdx.x * 64;
  int d0 = blockIdx.y * 64;
  int hkv = blockIdx.z;
  int tx = threadIdx.x & 63, ty = threadIdx.x >> 6;  // 64 x 4
#pragma unroll
  for (int i = 0; i < 64; i += 4)
    t[i + ty][tx] = QKV[(size_t)(s0 + i + ty) * QKV_N + HID + NKV * HD + hkv * HD + d0 + tx];
  __syncthreads();
#pragma unroll
  for (int i = 0; i < 64; i += 4)
    Vt[((size_t)hkv * HD + d0 + i + ty) * S_LEN + s0 + tx] = t[tx][i + ty];
}

// ---------------- flash attention: QB=64 q-rows/block, KT=64, causal, GQA ----------------
__global__ __launch_bounds__(256, 2) void attn_kernel(
    const ushort* __restrict__ QKV, const ushort* __restrict__ Vt, ushort* __restrict__ AO) {
  constexpr float SCALE = 0.08838834764831845f;  // 1/sqrt(128)
  __shared__ ushort k_lds[64 * 128];   // [krow][128 d], 16B chunks XOR-swizzled by (row&7)
  __shared__ ushort v_lds[128 * 64];   // [d][64 s], chunks XOR-swizzled by (row&7)
  __shared__ ushort p_lds[4][16 * 80]; // per-wave P tile [16 q][64 k], padded to 80

  const int qb = blockIdx.x, h = blockIdx.y;
  const int hkv = h >> 2;
  const int q0 = qb * 64;
  const int tid = threadIdx.x, wid = tid >> 6, lane = tid & 63;
  const int l16 = lane & 15, lk = lane >> 4;

  // Q fragments (A operand): rows q0 + wid*16 + l16, k = d
  bf16x8 qf[4];
  {
    const ushort* qbase = QKV + (size_t)(q0 + wid * 16 + l16) * QKV_N + h * HD + lk * 8;
#pragma unroll
    for (int kk = 0; kk < 4; ++kk)
      qf[kk] = *reinterpret_cast<const bf16x8*>(qbase + kk * 32);
  }

  float m_run[4] = {-1e30f, -1e30f, -1e30f, -1e30f};
  float l_run[4] = {0.f, 0.f, 0.f, 0.f};
  f32x4 oacc[8] = {};
  const int row_g0 = q0 + wid * 16 + lk * 4;  // + r

  for (int kt = 0; kt <= qb; ++kt) {
    // stage K tile [64][128]: 1024 chunks; pre-swizzled global source (m173)
#pragma unroll
    for (int i = 0; i < 4; ++i) {
      int c = i * 256 + wid * 64 + lane;
      int row = c >> 4, ch = c & 15;
      int sch = ch ^ (row & 7);
      gload_lds16(QKV + (size_t)(kt * 64 + row) * QKV_N + HID + hkv * HD + sch * 8,
                  &k_lds[c * 8]);
    }
    // stage Vt tile [128][64]: 1024 chunks
#pragma unroll
    for (int i = 0; i < 4; ++i) {
      int c = i * 256 + wid * 64 + lane;
      int row = c >> 3, ch = c & 7;
      int sch = ch ^ (row & 7);
      gload_lds16(Vt + ((size_t)hkv * HD + row) * S_LEN + kt * 64 + sch * 8,
                  &v_lds[c * 8]);
    }
    __syncthreads();

    // S = Q K^T, 4 n-frags x 4 k-steps
    f32x4 sv[4];
#pragma unroll
    for (int nf = 0; nf < 4; ++nf) {
      f32x4 s = {};
#pragma unroll
      for (int kk = 0; kk < 4; ++kk) {
        int krow = nf * 16 + l16;
        int chunk = (kk * 4 + lk) ^ (krow & 7);
        bf16x8 kf = *reinterpret_cast<const bf16x8*>(&k_lds[krow * 128 + chunk * 8]);
        s = __builtin_amdgcn_mfma_f32_16x16x32_bf16(qf[kk], kf, s, 0, 0, 0);
      }
      sv[nf] = s * SCALE;
    }

    if (kt == qb) {  // diagonal tile: causal mask
#pragma unroll
      for (int nf = 0; nf < 4; ++nf) {
        int colg = kt * 64 + nf * 16 + l16;
#pragma unroll
        for (int r = 0; r < 4; ++r)
          if (colg > row_g0 + r) sv[nf][r] = -1e30f;
      }
    }

    // online softmax (rows live in 16-lane groups)
    float alpha[4];
#pragma unroll
    for (int r = 0; r < 4; ++r) {
      float mt = fmaxf(fmaxf(sv[0][r], sv[1][r]), fmaxf(sv[2][r], sv[3][r]));
#pragma unroll
      for (int mm = 1; mm < 16; mm <<= 1) mt = fmaxf(mt, __shfl_xor(mt, mm, 64));
      float mn = fmaxf(m_run[r], mt);
      alpha[r] = __expf(m_run[r] - mn);
      float ls = 0.f;
#pragma unroll
      for (int nf = 0; nf < 4; ++nf) {
        float p = __expf(sv[nf][r] - mn);
        sv[nf][r] = p;
        ls += p;
      }
#pragma unroll
      for (int mm = 1; mm < 16; mm <<= 1) ls += __shfl_xor(ls, mm, 64);
      l_run[r] = l_run[r] * alpha[r] + ls;
      m_run[r] = mn;
    }

    // P -> LDS (bf16), O rescale
#pragma unroll
    for (int nf = 0; nf < 4; ++nf)
#pragma unroll
      for (int r = 0; r < 4; ++r)
        p_lds[wid][(lk * 4 + r) * 80 + nf * 16 + l16] = f2bf(sv[nf][r]);
#pragma unroll
    for (int o = 0; o < 8; ++o)
#pragma unroll
      for (int r = 0; r < 4; ++r)
        oacc[o][r] *= alpha[r];

    // O += P V  (A = P rows from p_lds, B = Vt rows from v_lds)
#pragma unroll
    for (int kc = 0; kc < 2; ++kc) {
      bf16x8 pf = *reinterpret_cast<const bf16x8*>(&p_lds[wid][l16 * 80 + kc * 32 + lk * 8]);
#pragma unroll
      for (int o = 0; o < 8; ++o) {
        int vrow = o * 16 + l16;
        int chunk = (kc * 4 + lk) ^ (vrow & 7);
        bf16x8 vf = *reinterpret_cast<const bf16x8*>(&v_lds[vrow * 64 + chunk * 8]);
        oacc[o] = __builtin_amdgcn_mfma_f32_16x16x32_bf16(pf, vf, oacc[o], 0, 0, 0);
      }
    }
    __syncthreads();  // all LDS reads done before next stage
  }

  // epilogue: O / l -> AO bf16
#pragma unroll
  for (int o = 0; o < 8; ++o)
#pragma unroll
    for (int r = 0; r < 4; ++r) {
      float v = oacc[o][r] / l_run[r];
      AO[(size_t)(row_g0 + r) * HID + h * HD + o * 16 + l16] = f2bf(v);
    }
}

// ---------------- launcher ----------------
extern "C" void kernel_launch(void* const* d_in, const int* in_sizes, int n_in,
                              void* d_out, int out_size, void* d_ws, size_t ws_size,
                              hipStream_t stream) {
  (void)in_sizes; (void)n_in; (void)out_size;
  const float* hs = (const float*)d_in[0];
  const float* Wq = (const float*)d_in[1];
  const float* Wk = (const float*)d_in[2];
  const float* Wv = (const float*)d_in[3];
  const float* Wo = (const float*)d_in[4];
  float* out = (float*)d_out;

  // workspace layout (bytes)
  char* ws = (char*)d_ws;
  const size_t OFF_HSB   = 0;                         // 2048*4096 bf16 = 16 MB
  const size_t OFF_WQKVT = OFF_HSB + 16777216;        // 6144*4096 bf16 = 48 MB
  const size_t OFF_WOT   = OFF_WQKVT + 50331648;      // 4096*4096 bf16 = 32 MB
  const size_t OFF_QKV   = OFF_WOT + 33554432;        // 2048*6144 bf16 = 24 MB
  const size_t OFF_VT    = OFF_QKV + 25165824;        // 8*128*2048 bf16 = 4 MB
  const size_t OFF_AO    = OFF_VT + 4194304;          // 2048*4096 bf16 = 16 MB
  if (ws_size < OFF_AO + 16777216) return;            // ~140 MB needed

  ushort* hsb   = (ushort*)(ws + OFF_HSB);
  ushort* WqkvT = (ushort*)(ws + OFF_WQKVT);
  ushort* WoT   = (ushort*)(ws + OFF_WOT);
  ushort* QKV   = (ushort*)(ws + OFF_QKV);
  ushort* Vt    = (ushort*)(ws + OFF_VT);
  ushort* AO    = (ushort*)(ws + OFF_AO);

  cast_f32_bf16<<<8192, 256, 0, stream>>>(hs, hsb, S_LEN * HID);
  transpose_cast<<<dim3(4096 / 32, 4096 / 32), 256, 0, stream>>>(Wq, WqkvT, HID, 4096);
  transpose_cast<<<dim3(1024 / 32, 4096 / 32), 256, 0, stream>>>(Wk, WqkvT + (size_t)4096 * HID, HID, 1024);
  transpose_cast<<<dim3(1024 / 32, 4096 / 32), 256, 0, stream>>>(Wv, WqkvT + (size_t)5120 * HID, HID, 1024);
  transpose_cast<<<dim3(4096 / 32, 4096 / 32), 256, 0, stream>>>(Wo, WoT, 4096, HID);

  gemm_bt<true><<<dim3(QKV_N / 128, S_LEN / 128), 256, 0, stream>>>(hsb, WqkvT, QKV, S_LEN, QKV_N, HID);
  rope_kernel<<<(S_LEN * 40 * 8) / 256, 256, 0, stream>>>(QKV);
  transpose_v<<<dim3(S_LEN / 64, HD / 64, NKV), 256, 0, stream>>>(QKV, Vt);
  attn_kernel<<<dim3(S_LEN / 64, NH), 256, 0, stream>>>(QKV, Vt, AO);
  gemm_bt<false><<<dim3(HID / 128, S_LEN / 128), 256, 0, stream>>>(AO, WoT, out, S_LEN, HID, HID);
}

// Round 2
// 439.138 us; speedup vs baseline: 1.0142x; 1.0142x over previous
//
#include <hip/hip_runtime.h>
#include <cstdint>
#include <cstddef>

typedef __attribute__((ext_vector_type(4))) float f32x4;
typedef __attribute__((ext_vector_type(8))) short bf16x8;

#define S_LEN   2048
#define HID     4096
#define NH      32
#define NKV     8
#define HD      128
#define QKV_N   6144   /* 4096 Q + 1024 K + 1024 V */

typedef const __attribute__((address_space(1))) unsigned int* gptr_t;
typedef __attribute__((address_space(3))) unsigned int* lptr_t;

__device__ __forceinline__ void gload_lds16(const void* g, void* l) {
  __builtin_amdgcn_global_load_lds((gptr_t)g, (lptr_t)l, 16, 0, 0);
}

__device__ __forceinline__ ushort f2bf(float f) {
  union { float f; uint32_t u; } v; v.f = f;
  uint32_t r = v.u + 0x7FFFu + ((v.u >> 16) & 1u);
  return (ushort)(r >> 16);
}
__device__ __forceinline__ float bf2f(ushort u) {
  union { uint32_t u; float f; } v; v.u = ((uint32_t)u) << 16;
  return v.f;
}

// ---------------- cast f32 -> bf16 (vectorized) ----------------
__global__ void cast_f32_bf16(const float* __restrict__ in, ushort* __restrict__ out, int n) {
  int i = (blockIdx.x * 256 + threadIdx.x) * 4;
  if (i >= n) return;
  float4 v = *reinterpret_cast<const float4*>(in + i);
  ushort4 o;
  o.x = f2bf(v.x); o.y = f2bf(v.y); o.z = f2bf(v.z); o.w = f2bf(v.w);
  *reinterpret_cast<ushort4*>(out + i) = o;
}

// ---------------- transpose + cast: in f32 [R][C] -> out bf16 [C][R] ----------------
__global__ void transpose_cast(const float* __restrict__ in, ushort* __restrict__ out, int R, int C) {
  __shared__ float t[32][33];
  int tx = threadIdx.x & 31, ty = threadIdx.x >> 5;  // 32 x 8
  int r0 = blockIdx.y * 32, c0 = blockIdx.x * 32;
#pragma unroll
  for (int i = 0; i < 32; i += 8)
    t[ty + i][tx] = in[(size_t)(r0 + ty + i) * C + c0 + tx];
  __syncthreads();
#pragma unroll
  for (int i = 0; i < 32; i += 8)
    out[(size_t)(c0 + ty + i) * R + r0 + tx] = f2bf(t[tx][ty + i]);
}

// ---------------- GEMM: C[M][N] = A[M][K] * B^T  (B stored [N][K]), bf16 in, fp32 acc ----------------
// m97 structure: 128x128 tile, BK=32, 4 waves (2x2), each wave 64x64 (4x4 frags of 16x16x32)
template <bool BF16_OUT>
__global__ __launch_bounds__(256, 2) void gemm_bt(
    const ushort* __restrict__ A, const ushort* __restrict__ B,
    void* __restrict__ Cp, int M, int N, int K) {
  __shared__ ushort a_lds[128 * 32];
  __shared__ ushort b_lds[128 * 32];
  const int tid = threadIdx.x;
  const int wid = tid >> 6, lane = tid & 63;
  const int l16 = lane & 15, lk = lane >> 4;
  const int wr = wid >> 1, wc = wid & 1;
  const size_t a_row0 = (size_t)blockIdx.y * 128;
  const size_t b_row0 = (size_t)blockIdx.x * 128;

  f32x4 acc[4][4] = {};

  for (int kt = 0; kt < K; kt += 32) {
    __syncthreads();  // prior-iteration LDS reads complete before overwrite
#pragma unroll
    for (int i = 0; i < 2; ++i) {
      int c = i * 256 + wid * 64 + lane;   // 16B chunk index, 512 chunks per tile
      int row = c >> 2, cc = c & 3;        // 4 chunks per 64B row
      gload_lds16(A + (a_row0 + row) * K + kt + cc * 8, &a_lds[c * 8]);
      gload_lds16(B + (b_row0 + row) * K + kt + cc * 8, &b_lds[c * 8]);
    }
    __syncthreads();  // drains vmcnt: LDS tiles ready

    bf16x8 af[4], bf[4];
#pragma unroll
    for (int m = 0; m < 4; ++m)
      af[m] = *reinterpret_cast<const bf16x8*>(&a_lds[(wr * 64 + m * 16 + l16) * 32 + lk * 8]);
#pragma unroll
    for (int n = 0; n < 4; ++n)
      bf[n] = *reinterpret_cast<const bf16x8*>(&b_lds[(wc * 64 + n * 16 + l16) * 32 + lk * 8]);
#pragma unroll
    for (int m = 0; m < 4; ++m)
#pragma unroll
      for (int n = 0; n < 4; ++n)
        acc[m][n] = __builtin_amdgcn_mfma_f32_16x16x32_bf16(af[m], bf[n], acc[m][n], 0, 0, 0);
  }

#pragma unroll
  for (int m = 0; m < 4; ++m) {
    int row_b = wr * 64 + m * 16 + lk * 4;
#pragma unroll
    for (int n = 0; n < 4; ++n) {
      int col = (int)b_row0 + wc * 64 + n * 16 + l16;
#pragma unroll
      for (int r = 0; r < 4; ++r) {
        size_t row = a_row0 + row_b + r;
        if constexpr (BF16_OUT)
          ((ushort*)Cp)[row * N + col] = f2bf(acc[m][n][r]);
        else
          ((float*)Cp)[row * N + col] = acc[m][n][r];
      }
    }
  }
}

// ---------------- RoPE in-place on Q (cols 0..4095) and K (cols 4096..5119) of QKV ----------------
__global__ void rope_kernel(ushort* __restrict__ QKV) {
  int idx = blockIdx.x * 256 + threadIdx.x;  // 2048 * 40 * 8 threads
  int dg = idx & 7;
  int t = idx >> 3;
  int s = t / 40;
  int hh = t - s * 40;
  if (s >= S_LEN) return;
  int col = (hh < NH) ? hh * HD : HID + (hh - NH) * HD;
  ushort* base = QKV + (size_t)s * QKV_N + col + dg * 8;

  union U { uint4 v; ushort u[8]; };
  U L, H, OL, OH;
  L.v = *reinterpret_cast<const uint4*>(base);
  H.v = *reinterpret_cast<const uint4*>(base + 64);
  const float C0 = 13.287712379549449f / 64.0f;  // log2(10000)/64
#pragma unroll
  for (int j = 0; j < 8; ++j) {
    int d = dg * 8 + j;
    float invf = exp2f(-(float)d * C0);
    float ang = (float)s * invf;
    float sn, cs;
    sincosf(ang, &sn, &cs);
    float xl = bf2f(L.u[j]), xh = bf2f(H.u[j]);
    OL.u[j] = f2bf(xl * cs - xh * sn);
    OH.u[j] = f2bf(xh * cs + xl * sn);
  }
  *reinterpret_cast<uint4*>(base) = OL.v;
  *reinterpret_cast<uint4*>(base + 64) = OH.v;
}

// ---------------- V slice of QKV -> Vt[8][128][2048] ----------------
__global__ void transpose_v(const ushort* __restrict__ QKV, ushort* __restrict__ Vt) {
  __shared__ ushort t[64][65];
  int s0 = blockIdx.x * 64;
  int d0 = blockIdx.y * 64;
  int hkv = blockIdx.z;
  int tx = threadIdx.x & 63, ty = threadIdx.x >> 6;  // 64 x 4
#pragma unroll
  for (int i = 0; i < 64; i += 4)
    t[i + ty][tx] = QKV[(size_t)(s0 + i + ty) * QKV_N + HID + NKV * HD + hkv * HD + d0 + tx];
  __syncthreads();
#pragma unroll
  for (int i = 0; i < 64; i += 4)
    Vt[((size_t)hkv * HD + d0 + i + ty) * S_LEN + s0 + tx] = t[tx][i + ty];
}

// ---------------- flash attention: QB=64 q-rows/block, KT=64, causal, GQA ----------------
// Double-buffered K/V staging (T3-minimal 2-phase), XOR-swizzled P tile, heavy-qb-first.
__global__ __launch_bounds__(256, 2) void attn_kernel(
    const ushort* __restrict__ QKV, const ushort* __restrict__ Vt, ushort* __restrict__ AO) {
  constexpr float SCALE = 0.08838834764831845f;  // 1/sqrt(128)
  __shared__ ushort k_lds[2][64 * 128];   // [krow][128 d], 16B chunks XOR-swizzled by (row&7)
  __shared__ ushort v_lds[2][128 * 64];   // [d][64 s], chunks XOR-swizzled by (row&7)
  __shared__ ushort p_lds[4][16 * 64];    // per-wave P [16 q][64 k], chunk ^ (q&7) swizzle

  const int qb = (int)gridDim.x - 1 - (int)blockIdx.x;  // heavy tiles dispatch first
  const int h = blockIdx.y;
  const int hkv = h >> 2;
  const int q0 = qb * 64;
  const int tid = threadIdx.x, wid = tid >> 6, lane = tid & 63;
  const int l16 = lane & 15, lk = lane >> 4;

  // Q fragments (A operand): rows q0 + wid*16 + l16, k = d
  bf16x8 qf[4];
  {
    const ushort* qbase = QKV + (size_t)(q0 + wid * 16 + l16) * QKV_N + h * HD + lk * 8;
#pragma unroll
    for (int kk = 0; kk < 4; ++kk)
      qf[kk] = *reinterpret_cast<const bf16x8*>(qbase + kk * 32);
  }

  float m_run[4] = {-1e30f, -1e30f, -1e30f, -1e30f};
  float l_run[4] = {0.f, 0.f, 0.f, 0.f};
  f32x4 oacc[8] = {};
  const int row_g0 = q0 + wid * 16 + lk * 4;  // + r

  auto stageKV = [&](int buf, int kt) {
#pragma unroll
    for (int i = 0; i < 4; ++i) {
      int c = i * 256 + wid * 64 + lane;
      int row = c >> 4, ch = c & 15;
      int sch = ch ^ (row & 7);
      gload_lds16(QKV + (size_t)(kt * 64 + row) * QKV_N + HID + hkv * HD + sch * 8,
                  &k_lds[buf][c * 8]);
    }
#pragma unroll
    for (int i = 0; i < 4; ++i) {
      int c = i * 256 + wid * 64 + lane;
      int row = c >> 3, ch = c & 7;
      int sch = ch ^ (row & 7);
      gload_lds16(Vt + ((size_t)hkv * HD + row) * S_LEN + (size_t)kt * 64 + sch * 8,
                  &v_lds[buf][c * 8]);
    }
  };

  stageKV(0, 0);
  __syncthreads();  // drain prologue stage

  const int nt = qb + 1;
  for (int kt = 0; kt < nt; ++kt) {
    const int cur = kt & 1;
    if (kt + 1 < nt) stageKV(cur ^ 1, kt + 1);  // overlap next-tile loads with compute

    // S = Q K^T, 4 n-frags x 4 k-steps
    f32x4 sv[4];
    __builtin_amdgcn_s_setprio(1);
#pragma unroll
    for (int nf = 0; nf < 4; ++nf) {
      f32x4 s = {};
#pragma unroll
      for (int kk = 0; kk < 4; ++kk) {
        int krow = nf * 16 + l16;
        int chunk = (kk * 4 + lk) ^ (krow & 7);
        bf16x8 kf = *reinterpret_cast<const bf16x8*>(&k_lds[cur][krow * 128 + chunk * 8]);
        s = __builtin_amdgcn_mfma_f32_16x16x32_bf16(qf[kk], kf, s, 0, 0, 0);
      }
      sv[nf] = s * SCALE;
    }
    __builtin_amdgcn_s_setprio(0);

    if (kt == qb) {  // diagonal tile: causal mask
#pragma unroll
      for (int nf = 0; nf < 4; ++nf) {
        int colg = kt * 64 + nf * 16 + l16;
#pragma unroll
        for (int r = 0; r < 4; ++r)
          if (colg > row_g0 + r) sv[nf][r] = -1e30f;
      }
    }

    // online softmax (rows live in 16-lane groups)
    float alpha[4];
#pragma unroll
    for (int r = 0; r < 4; ++r) {
      float mt = fmaxf(fmaxf(sv[0][r], sv[1][r]), fmaxf(sv[2][r], sv[3][r]));
#pragma unroll
      for (int mm = 1; mm < 16; mm <<= 1) mt = fmaxf(mt, __shfl_xor(mt, mm, 64));
      float mn = fmaxf(m_run[r], mt);
      alpha[r] = __expf(m_run[r] - mn);
      float ls = 0.f;
#pragma unroll
      for (int nf = 0; nf < 4; ++nf) {
        float p = __expf(sv[nf][r] - mn);
        sv[nf][r] = p;
        ls += p;
      }
#pragma unroll
      for (int mm = 1; mm < 16; mm <<= 1) ls += __shfl_xor(ls, mm, 64);
      l_run[r] = l_run[r] * alpha[r] + ls;
      m_run[r] = mn;
    }

    // P -> LDS (bf16, swizzled like k_lds so reads are the proven pattern), O rescale
#pragma unroll
    for (int nf = 0; nf < 4; ++nf)
#pragma unroll
      for (int r = 0; r < 4; ++r) {
        int prow = lk * 4 + r;
        int colu = nf * 16 + l16;
        int sch = (colu >> 3) ^ (prow & 7);
        p_lds[wid][prow * 64 + sch * 8 + (colu & 7)] = f2bf(sv[nf][r]);
      }
#pragma unroll
    for (int o = 0; o < 8; ++o)
#pragma unroll
      for (int r = 0; r < 4; ++r)
        oacc[o][r] *= alpha[r];

    // O += P V  (A = P rows from p_lds, B = Vt rows from v_lds)
    __builtin_amdgcn_s_setprio(1);
#pragma unroll
    for (int kc = 0; kc < 2; ++kc) {
      int pch = (kc * 4 + lk) ^ (l16 & 7);
      bf16x8 pf = *reinterpret_cast<const bf16x8*>(&p_lds[wid][l16 * 64 + pch * 8]);
#pragma unroll
      for (int o = 0; o < 8; ++o) {
        int vrow = o * 16 + l16;
        int chunk = (kc * 4 + lk) ^ (vrow & 7);
        bf16x8 vf = *reinterpret_cast<const bf16x8*>(&v_lds[cur][vrow * 64 + chunk * 8]);
        oacc[o] = __builtin_amdgcn_mfma_f32_16x16x32_bf16(pf, vf, oacc[o], 0, 0, 0);
      }
    }
    __builtin_amdgcn_s_setprio(0);

    __syncthreads();  // drains next-tile staging (vmcnt) + guards LDS reuse
  }

  // epilogue: O / l -> AO bf16
#pragma unroll
  for (int o = 0; o < 8; ++o)
#pragma unroll
    for (int r = 0; r < 4; ++r) {
      float v = oacc[o][r] / l_run[r];
      AO[(size_t)(row_g0 + r) * HID + h * HD + o * 16 + l16] = f2bf(v);
    }
}

// ---------------- launcher ----------------
extern "C" void kernel_launch(void* const* d_in, const int* in_sizes, int n_in,
                              void* d_out, int out_size, void* d_ws, size_t ws_size,
                              hipStream_t stream) {
  (void)in_sizes; (void)n_in; (void)out_size;
  const float* hs = (const float*)d_in[0];
  const float* Wq = (const float*)d_in[1];
  const float* Wk = (const float*)d_in[2];
  const float* Wv = (const float*)d_in[3];
  const float* Wo = (const float*)d_in[4];
  float* out = (float*)d_out;

  // workspace layout (bytes)
  char* ws = (char*)d_ws;
  const size_t OFF_HSB   = 0;                         // 2048*4096 bf16 = 16 MB
  const size_t OFF_WQKVT = OFF_HSB + 16777216;        // 6144*4096 bf16 = 48 MB
  const size_t OFF_WOT   = OFF_WQKVT + 50331648;      // 4096*4096 bf16 = 32 MB
  const size_t OFF_QKV   = OFF_WOT + 33554432;        // 2048*6144 bf16 = 24 MB
  const size_t OFF_VT    = OFF_QKV + 25165824;        // 8*128*2048 bf16 = 4 MB
  const size_t OFF_AO    = OFF_VT + 4194304;          // 2048*4096 bf16 = 16 MB
  if (ws_size < OFF_AO + 16777216) return;            // ~140 MB needed

  ushort* hsb   = (ushort*)(ws + OFF_HSB);
  ushort* WqkvT = (ushort*)(ws + OFF_WQKVT);
  ushort* WoT   = (ushort*)(ws + OFF_WOT);
  ushort* QKV   = (ushort*)(ws + OFF_QKV);
  ushort* Vt    = (ushort*)(ws + OFF_VT);
  ushort* AO    = (ushort*)(ws + OFF_AO);

  cast_f32_bf16<<<8192, 256, 0, stream>>>(hs, hsb, S_LEN * HID);
  transpose_cast<<<dim3(4096 / 32, 4096 / 32), 256, 0, stream>>>(Wq, WqkvT, HID, 4096);
  transpose_cast<<<dim3(1024 / 32, 4096 / 32), 256, 0, stream>>>(Wk, WqkvT + (size_t)4096 * HID, HID, 1024);
  transpose_cast<<<dim3(1024 / 32, 4096 / 32), 256, 0, stream>>>(Wv, WqkvT + (size_t)5120 * HID, HID, 1024);
  transpose_cast<<<dim3(4096 / 32, 4096 / 32), 256, 0, stream>>>(Wo, WoT, 4096, HID);

  gemm_bt<true><<<dim3(QKV_N / 128, S_LEN / 128), 256, 0, stream>>>(hsb, WqkvT, QKV, S_LEN, QKV_N, HID);
  rope_kernel<<<(S_LEN * 40 * 8) / 256, 256, 0, stream>>>(QKV);
  transpose_v<<<dim3(S_LEN / 64, HD / 64, NKV), 256, 0, stream>>>(QKV, Vt);
  attn_kernel<<<dim3(S_LEN / 64, NH), 256, 0, stream>>>(QKV, Vt, AO);
  gemm_bt<false><<<dim3(HID / 128, S_LEN / 128), 256, 0, stream>>>(AO, WoT, out, S_LEN, HID, HID);
}

// Round 4
// 369.296 us; speedup vs baseline: 1.2060x; 1.1891x over previous
//
#include <hip/hip_runtime.h>
#include <cstdint>
#include <cstddef>

typedef __attribute__((ext_vector_type(4))) float f32x4;
typedef __attribute__((ext_vector_type(16))) float f32x16;
typedef __attribute__((ext_vector_type(8))) short bf16x8;
typedef __attribute__((ext_vector_type(2))) unsigned int u32x2;

#define S_LEN   2048
#define HID     4096
#define NH      32
#define NKV     8
#define HD      128
#define QKV_N   6144   /* 4096 Q + 1024 K + 1024 V */

typedef const __attribute__((address_space(1))) unsigned int* gptr_t;
typedef __attribute__((address_space(3))) unsigned int* lptr_t;

__device__ __forceinline__ void gload_lds16(const void* g, void* l) {
  __builtin_amdgcn_global_load_lds((gptr_t)g, (lptr_t)l, 16, 0, 0);
}

__device__ __forceinline__ ushort f2bf(float f) {
  union { float f; uint32_t u; } v; v.f = f;
  uint32_t r = v.u + 0x7FFFu + ((v.u >> 16) & 1u);
  return (ushort)(r >> 16);
}
__device__ __forceinline__ float bf2f(ushort u) {
  union { uint32_t u; float f; } v; v.u = ((uint32_t)u) << 16;
  return v.f;
}

// ---------------- cast f32 -> bf16 (vectorized) ----------------
__global__ void cast_f32_bf16(const float* __restrict__ in, ushort* __restrict__ out, int n) {
  int i = (blockIdx.x * 256 + threadIdx.x) * 4;
  if (i >= n) return;
  float4 v = *reinterpret_cast<const float4*>(in + i);
  ushort4 o;
  o.x = f2bf(v.x); o.y = f2bf(v.y); o.z = f2bf(v.z); o.w = f2bf(v.w);
  *reinterpret_cast<ushort4*>(out + i) = o;
}

// ---------------- transpose + cast: in f32 [R][C] -> out bf16 [C][R] ----------------
__global__ void transpose_cast(const float* __restrict__ in, ushort* __restrict__ out, int R, int C) {
  __shared__ float t[32][33];
  int tx = threadIdx.x & 31, ty = threadIdx.x >> 5;  // 32 x 8
  int r0 = blockIdx.y * 32, c0 = blockIdx.x * 32;
#pragma unroll
  for (int i = 0; i < 32; i += 8)
    t[ty + i][tx] = in[(size_t)(r0 + ty + i) * C + c0 + tx];
  __syncthreads();
#pragma unroll
  for (int i = 0; i < 32; i += 8)
    out[(size_t)(c0 + ty + i) * R + r0 + tx] = f2bf(t[tx][ty + i]);
}

// ---------------- GEMM: C[M][N] = A[M][K] * B^T  (B stored [N][K]), bf16 in, fp32 acc ----------------
// m97 structure: 128x128 tile, BK=32, 4 waves (2x2), each wave 64x64 (4x4 frags of 16x16x32)
template <bool BF16_OUT>
__global__ __launch_bounds__(256, 2) void gemm_bt(
    const ushort* __restrict__ A, const ushort* __restrict__ B,
    void* __restrict__ Cp, int M, int N, int K) {
  __shared__ ushort a_lds[128 * 32];
  __shared__ ushort b_lds[128 * 32];
  const int tid = threadIdx.x;
  const int wid = tid >> 6, lane = tid & 63;
  const int l16 = lane & 15, lk = lane >> 4;
  const int wr = wid >> 1, wc = wid & 1;
  const size_t a_row0 = (size_t)blockIdx.y * 128;
  const size_t b_row0 = (size_t)blockIdx.x * 128;

  f32x4 acc[4][4] = {};

  for (int kt = 0; kt < K; kt += 32) {
    __syncthreads();  // prior-iteration LDS reads complete before overwrite
#pragma unroll
    for (int i = 0; i < 2; ++i) {
      int c = i * 256 + wid * 64 + lane;   // 16B chunk index, 512 chunks per tile
      int row = c >> 2, cc = c & 3;        // 4 chunks per 64B row
      gload_lds16(A + (a_row0 + row) * K + kt + cc * 8, &a_lds[c * 8]);
      gload_lds16(B + (b_row0 + row) * K + kt + cc * 8, &b_lds[c * 8]);
    }
    __syncthreads();  // drains vmcnt: LDS tiles ready

    bf16x8 af[4], bf[4];
#pragma unroll
    for (int m = 0; m < 4; ++m)
      af[m] = *reinterpret_cast<const bf16x8*>(&a_lds[(wr * 64 + m * 16 + l16) * 32 + lk * 8]);
#pragma unroll
    for (int n = 0; n < 4; ++n)
      bf[n] = *reinterpret_cast<const bf16x8*>(&b_lds[(wc * 64 + n * 16 + l16) * 32 + lk * 8]);
#pragma unroll
    for (int m = 0; m < 4; ++m)
#pragma unroll
      for (int n = 0; n < 4; ++n)
        acc[m][n] = __builtin_amdgcn_mfma_f32_16x16x32_bf16(af[m], bf[n], acc[m][n], 0, 0, 0);
  }

#pragma unroll
  for (int m = 0; m < 4; ++m) {
    int row_b = wr * 64 + m * 16 + lk * 4;
#pragma unroll
    for (int n = 0; n < 4; ++n) {
      int col = (int)b_row0 + wc * 64 + n * 16 + l16;
#pragma unroll
      for (int r = 0; r < 4; ++r) {
        size_t row = a_row0 + row_b + r;
        if constexpr (BF16_OUT)
          ((ushort*)Cp)[row * N + col] = f2bf(acc[m][n][r]);
        else
          ((float*)Cp)[row * N + col] = acc[m][n][r];
      }
    }
  }
}

// ---------------- RoPE in-place on Q (cols 0..4095) and K (cols 4096..5119) of QKV ----------------
__global__ void rope_kernel(ushort* __restrict__ QKV) {
  int idx = blockIdx.x * 256 + threadIdx.x;  // 2048 * 40 * 8 threads
  int dg = idx & 7;
  int t = idx >> 3;
  int s = t / 40;
  int hh = t - s * 40;
  if (s >= S_LEN) return;
  int col = (hh < NH) ? hh * HD : HID + (hh - NH) * HD;
  ushort* base = QKV + (size_t)s * QKV_N + col + dg * 8;

  union U { uint4 v; ushort u[8]; };
  U L, H, OL, OH;
  L.v = *reinterpret_cast<const uint4*>(base);
  H.v = *reinterpret_cast<const uint4*>(base + 64);
  const float C0 = 13.287712379549449f / 64.0f;  // log2(10000)/64
#pragma unroll
  for (int j = 0; j < 8; ++j) {
    int d = dg * 8 + j;
    float invf = exp2f(-(float)d * C0);
    float ang = (float)s * invf;
    float sn, cs;
    sincosf(ang, &sn, &cs);
    float xl = bf2f(L.u[j]), xh = bf2f(H.u[j]);
    OL.u[j] = f2bf(xl * cs - xh * sn);
    OH.u[j] = f2bf(xh * cs + xl * sn);
  }
  *reinterpret_cast<uint4*>(base) = OL.v;
  *reinterpret_cast<uint4*>(base + 64) = OH.v;
}

// ---------------- V slice of QKV -> Vt[8][128][2048] ----------------
__global__ void transpose_v(const ushort* __restrict__ QKV, ushort* __restrict__ Vt) {
  __shared__ ushort t[64][65];
  int s0 = blockIdx.x * 64;
  int d0 = blockIdx.y * 64;
  int hkv = blockIdx.z;
  int tx = threadIdx.x & 63, ty = threadIdx.x >> 6;  // 64 x 4
#pragma unroll
  for (int i = 0; i < 64; i += 4)
    t[i + ty][tx] = QKV[(size_t)(s0 + i + ty) * QKV_N + HID + NKV * HD + hkv * HD + d0 + tx];
  __syncthreads();
#pragma unroll
  for (int i = 0; i < 64; i += 4)
    Vt[((size_t)hkv * HD + d0 + i + ty) * S_LEN + s0 + tx] = t[tx][i + ty];
}

// ---------------- flash attention: swapped-QK^T 32x32 MFMA, in-register softmax ----------------
// QBLK=128 (4 waves x 32 q-rows), KVBLK=64, double-buffered K/V staging, causal, GQA.
// S^T = mfma(K, Q): lane(q=lane&31, hi=lane>>5) holds P[k=kf*32+crow(r,hi)][q=lane&31].
// Softmax fully in-register (one q-row per lane). P packed to PV B-operand via
// v_cvt_pk_bf16_f32 + permlane32_swap (T12). PV computed as mfma(A=V^T, B=P) so the
// output's q maps to lane&31 (own lane) -> per-lane alpha/l are correct.
__global__ __launch_bounds__(256, 2) void attn_kernel(
    const ushort* __restrict__ QKV, const ushort* __restrict__ Vt, ushort* __restrict__ AO) {
  constexpr float SCALE = 0.08838834764831845f;  // 1/sqrt(128)
  __shared__ ushort k_lds[2][64 * 128];   // [krow][128 d], 16B chunks XOR-swizzled by (row&7)
  __shared__ ushort v_lds[2][128 * 64];   // [d][64 s], 16B chunks XOR-swizzled by (row&7)

  const int qb = blockIdx.x;              // 0..15
  const int h = blockIdx.y;
  const int hkv = h >> 2;
  const int q0 = qb * 128;
  const int tid = threadIdx.x, wid = tid >> 6, lane = tid & 63;
  const int l32 = lane & 31;
  const int hi = lane >> 5;
  const int qg = q0 + wid * 32 + l32;     // this lane's q row

  // Q fragments (B operand of QK^T): qf[ds][j] = Q[qg][ds*16 + hi*8 + j]
  bf16x8 qf[8];
  {
    const ushort* qrow = QKV + (size_t)qg * QKV_N + h * HD + hi * 8;
#pragma unroll
    for (int ds = 0; ds < 8; ++ds)
      qf[ds] = *reinterpret_cast<const bf16x8*>(qrow + ds * 16);
  }

  float m_run = -1e30f, l_run = 0.f;
  f32x16 oacc[4] = {};   // oacc[f][r] = O[q=l32][d = f*32 + crow(r,hi)]

  auto stageKV = [&](int buf, int kt) {
#pragma unroll
    for (int i = 0; i < 4; ++i) {
      int c = i * 256 + wid * 64 + lane;
      int row = c >> 4, ch = c & 15;
      int sch = ch ^ (row & 7);
      gload_lds16(QKV + (size_t)(kt * 64 + row) * QKV_N + HID + hkv * HD + sch * 8,
                  &k_lds[buf][c * 8]);
    }
#pragma unroll
    for (int i = 0; i < 4; ++i) {
      int c = i * 256 + wid * 64 + lane;
      int row = c >> 3, ch = c & 7;
      int sch = ch ^ (row & 7);
      gload_lds16(Vt + ((size_t)hkv * HD + row) * S_LEN + (size_t)kt * 64 + sch * 8,
                  &v_lds[buf][c * 8]);
    }
  };

  stageKV(0, 0);
  __syncthreads();  // drain prologue stage

  const int nt = 2 * qb + 2;
  for (int kt = 0; kt < nt; ++kt) {
    const int cur = kt & 1;
    if (kt + 1 < nt) stageKV(cur ^ 1, kt + 1);  // overlap next-tile loads with compute

    // wave-uniform: skip fully-masked tail tile
    if (kt * 64 <= q0 + wid * 32 + 31) {
      // S^T = K Q^T: p[kf*16+r] = P[k = kt*64 + kf*32 + crow(r,hi)][q = l32]
      float p[32];
      __builtin_amdgcn_s_setprio(1);
#pragma unroll
      for (int kf = 0; kf < 2; ++kf) {
        f32x16 s = {};
        int rk = kf * 32 + l32;
#pragma unroll
        for (int ds = 0; ds < 8; ++ds) {
          int c16 = (ds * 2 + hi) ^ (rk & 7);
          bf16x8 kfr = *reinterpret_cast<const bf16x8*>(&k_lds[cur][rk * 128 + c16 * 8]);
          s = __builtin_amdgcn_mfma_f32_32x32x16_bf16(kfr, qf[ds], s, 0, 0, 0);
        }
#pragma unroll
        for (int r = 0; r < 16; ++r) p[kf * 16 + r] = s[r] * SCALE;
      }
      __builtin_amdgcn_s_setprio(0);

      // causal mask (diagonal tiles only; wave-uniform gate)
      if (kt * 64 + 63 > q0 + wid * 32) {
#pragma unroll
        for (int kf = 0; kf < 2; ++kf)
#pragma unroll
          for (int r = 0; r < 16; ++r) {
            int kl = kf * 32 + (r & 3) + 8 * (r >> 2) + 4 * hi;
            if (kt * 64 + kl > qg) p[kf * 16 + r] = -1e30f;
          }
      }

      // in-register online softmax (one q-row per lane; hi pair holds disjoint k's)
      float mt = p[0];
#pragma unroll
      for (int i = 1; i < 32; ++i) mt = fmaxf(mt, p[i]);
      mt = fmaxf(mt, __shfl_xor(mt, 32, 64));
      float mn = fmaxf(m_run, mt);
      float alpha = __expf(m_run - mn);
      float ls = 0.f;
#pragma unroll
      for (int i = 0; i < 32; ++i) { p[i] = __expf(p[i] - mn); ls += p[i]; }
      ls += __shfl_xor(ls, 32, 64);
      l_run = l_run * alpha + ls;
      m_run = mn;
#pragma unroll
      for (int f = 0; f < 4; ++f)
#pragma unroll
        for (int r = 0; r < 16; ++r) oacc[f][r] *= alpha;  // own-lane q: correct now

      // pack P -> PV B-operand fragments (T12: cvt_pk + permlane32_swap)
      // pa[ks] elem j on lane l = P[q=l&31][k_local = ks*16 + 8*hi + j]
      union PW { uint32_t w[4]; bf16x8 v; } pa[4];
#pragma unroll
      for (int ks = 0; ks < 4; ++ks) {
        uint32_t x0, x1, y0, y1;
        asm("v_cvt_pk_bf16_f32 %0, %1, %2" : "=v"(x0) : "v"(p[8 * ks + 0]), "v"(p[8 * ks + 1]));
        asm("v_cvt_pk_bf16_f32 %0, %1, %2" : "=v"(x1) : "v"(p[8 * ks + 2]), "v"(p[8 * ks + 3]));
        asm("v_cvt_pk_bf16_f32 %0, %1, %2" : "=v"(y0) : "v"(p[8 * ks + 4]), "v"(p[8 * ks + 5]));
        asm("v_cvt_pk_bf16_f32 %0, %1, %2" : "=v"(y1) : "v"(p[8 * ks + 6]), "v"(p[8 * ks + 7]));
        u32x2 r0 = __builtin_amdgcn_permlane32_swap(x0, y0, false, false);
        u32x2 r1 = __builtin_amdgcn_permlane32_swap(x1, y1, false, false);
        pa[ks].w[0] = r0.x; pa[ks].w[1] = r1.x; pa[ks].w[2] = r0.y; pa[ks].w[3] = r1.y;
      }

      // O^T block: oacc[f] = mfma(A = V^T rows d=f*32+.., B = P cols q)
      __builtin_amdgcn_s_setprio(1);
#pragma unroll
      for (int ks = 0; ks < 4; ++ks) {
#pragma unroll
        for (int f = 0; f < 4; ++f) {
          int dv = f * 32 + l32;
          int c8 = (2 * ks + hi) ^ (dv & 7);
          bf16x8 vfr = *reinterpret_cast<const bf16x8*>(&v_lds[cur][dv * 64 + c8 * 8]);
          oacc[f] = __builtin_amdgcn_mfma_f32_32x32x16_bf16(vfr, pa[ks].v, oacc[f], 0, 0, 0);
        }
      }
      __builtin_amdgcn_s_setprio(0);
    }

    __syncthreads();  // drains next-tile staging (vmcnt) + guards LDS reuse
  }

  // epilogue: O / l -> AO bf16 (q = own lane; d = f*32 + 8*g + 4*hi + t)
  float inv_l = 1.0f / l_run;
  ushort* aorow = AO + (size_t)qg * HID + h * HD;
#pragma unroll
  for (int f = 0; f < 4; ++f)
#pragma unroll
    for (int g = 0; g < 4; ++g) {
      ushort4 o;
      o.x = f2bf(oacc[f][g * 4 + 0] * inv_l);
      o.y = f2bf(oacc[f][g * 4 + 1] * inv_l);
      o.z = f2bf(oacc[f][g * 4 + 2] * inv_l);
      o.w = f2bf(oacc[f][g * 4 + 3] * inv_l);
      *reinterpret_cast<ushort4*>(aorow + f * 32 + g * 8 + 4 * hi) = o;
    }
}

// ---------------- launcher ----------------
extern "C" void kernel_launch(void* const* d_in, const int* in_sizes, int n_in,
                              void* d_out, int out_size, void* d_ws, size_t ws_size,
                              hipStream_t stream) {
  (void)in_sizes; (void)n_in; (void)out_size;
  const float* hs = (const float*)d_in[0];
  const float* Wq = (const float*)d_in[1];
  const float* Wk = (const float*)d_in[2];
  const float* Wv = (const float*)d_in[3];
  const float* Wo = (const float*)d_in[4];
  float* out = (float*)d_out;

  // workspace layout (bytes)
  char* ws = (char*)d_ws;
  const size_t OFF_HSB   = 0;                         // 2048*4096 bf16 = 16 MB
  const size_t OFF_WQKVT = OFF_HSB + 16777216;        // 6144*4096 bf16 = 48 MB
  const size_t OFF_WOT   = OFF_WQKVT + 50331648;      // 4096*4096 bf16 = 32 MB
  const size_t OFF_QKV   = OFF_WOT + 33554432;        // 2048*6144 bf16 = 24 MB
  const size_t OFF_VT    = OFF_QKV + 25165824;        // 8*128*2048 bf16 = 4 MB
  const size_t OFF_AO    = OFF_VT + 4194304;          // 2048*4096 bf16 = 16 MB
  if (ws_size < OFF_AO + 16777216) return;            // ~140 MB needed

  ushort* hsb   = (ushort*)(ws + OFF_HSB);
  ushort* WqkvT = (ushort*)(ws + OFF_WQKVT);
  ushort* WoT   = (ushort*)(ws + OFF_WOT);
  ushort* QKV   = (ushort*)(ws + OFF_QKV);
  ushort* Vt    = (ushort*)(ws + OFF_VT);
  ushort* AO    = (ushort*)(ws + OFF_AO);

  cast_f32_bf16<<<8192, 256, 0, stream>>>(hs, hsb, S_LEN * HID);
  transpose_cast<<<dim3(4096 / 32, 4096 / 32), 256, 0, stream>>>(Wq, WqkvT, HID, 4096);
  transpose_cast<<<dim3(1024 / 32, 4096 / 32), 256, 0, stream>>>(Wk, WqkvT + (size_t)4096 * HID, HID, 1024);
  transpose_cast<<<dim3(1024 / 32, 4096 / 32), 256, 0, stream>>>(Wv, WqkvT + (size_t)5120 * HID, HID, 1024);
  transpose_cast<<<dim3(4096 / 32, 4096 / 32), 256, 0, stream>>>(Wo, WoT, 4096, HID);

  gemm_bt<true><<<dim3(QKV_N / 128, S_LEN / 128), 256, 0, stream>>>(hsb, WqkvT, QKV, S_LEN, QKV_N, HID);
  rope_kernel<<<(S_LEN * 40 * 8) / 256, 256, 0, stream>>>(QKV);
  transpose_v<<<dim3(S_LEN / 64, HD / 64, NKV), 256, 0, stream>>>(QKV, Vt);
  attn_kernel<<<dim3(S_LEN / 128, NH), 256, 0, stream>>>(QKV, Vt, AO);
  gemm_bt<false><<<dim3(HID / 128, S_LEN / 128), 256, 0, stream>>>(AO, WoT, out, S_LEN, HID, HID);
}